// Round 1
// baseline (2662.260 us; speedup 1.0000x reference)
//
#include <hip/hip_runtime.h>
#include <math.h>

// Problem constants
#define BB 2
#define TT 1024
#define CC 1024
#define HH 16
#define HD 64
#define SS 512
#define LL 1024
#define ST 1536   // S+T
#define MM 2560   // L+S+T
#define C3 3072   // 3*C

// ---------------------------------------------------------------------------
// Kernel 1: qkv = xcat @ w_attn, fused RoPE, scatter to Q/K/V in [B,H,seq,HD]
//   Q: [B,H,T,HD]   (only x-part queries; stm/long queries are dead)
//   K: [B,H,M,HD]   rows [L,M) written here, rows [0,L) by copy kernel
//   V: [B,H,M,HD]   same
// 64x64 tile, 256 threads, 4x4 micro-tile, K-step 16.
// ---------------------------------------------------------------------------
__global__ __launch_bounds__(256)
void qkv_rope_kernel(const float* __restrict__ x, const float* __restrict__ stm,
                     const float* __restrict__ w_attn,
                     float* __restrict__ Q, float* __restrict__ K, float* __restrict__ V)
{
    __shared__ float As[16][68];   // A transposed: As[k][m]
    __shared__ float Bs[16][68];   // Bs[k][n]
    const int b    = blockIdx.z;
    const int row0 = blockIdx.y * 64;   // row in xcat [0,1536)
    const int col0 = blockIdx.x * 64;   // col in [0,3072)
    const int tid  = threadIdx.x;
    const int tx = tid & 15, ty = tid >> 4;

    // loader indices
    const int ar = tid >> 2;          // 0..63  (tile row)
    const int ak = (tid & 3) << 2;    // 0,4,8,12
    const int bk = tid >> 4;          // 0..15  (k row)
    const int bn = (tid & 15) << 2;   // 0..60

    const int r_a = row0 + ar;
    const float* arow = (r_a < SS) ? (stm + ((size_t)b * SS + r_a) * CC)
                                   : (x   + ((size_t)b * TT + (r_a - SS)) * CC);

    float acc[4][4];
    #pragma unroll
    for (int i = 0; i < 4; i++)
        #pragma unroll
        for (int j = 0; j < 4; j++) acc[i][j] = 0.f;

    for (int k0 = 0; k0 < CC; k0 += 16) {
        float4 av = *(const float4*)(arow + k0 + ak);
        float4 bv = *(const float4*)(w_attn + (size_t)(k0 + bk) * C3 + col0 + bn);
        __syncthreads();
        As[ak + 0][ar] = av.x;
        As[ak + 1][ar] = av.y;
        As[ak + 2][ar] = av.z;
        As[ak + 3][ar] = av.w;
        *(float4*)&Bs[bk][bn] = bv;
        __syncthreads();
        #pragma unroll
        for (int kk = 0; kk < 16; kk++) {
            float4 a4 = *(float4*)&As[kk][ty * 4];
            float4 b4 = *(float4*)&Bs[kk][tx * 4];
            float aa[4] = {a4.x, a4.y, a4.z, a4.w};
            float bbv[4] = {b4.x, b4.y, b4.z, b4.w};
            #pragma unroll
            for (int i = 0; i < 4; i++)
                #pragma unroll
                for (int j = 0; j < 4; j++)
                    acc[i][j] = fmaf(aa[i], bbv[j], acc[i][j]);
        }
    }

    // Epilogue: RoPE (pairs are column-local since each thread owns 4 consecutive cols)
    #pragma unroll
    for (int i = 0; i < 4; i++) {
        const int r = row0 + ty * 4 + i;   // position in xcat == RoPE position
        #pragma unroll
        for (int j = 0; j < 4; j += 2) {
            const int c = col0 + tx * 4 + j;    // even
            float v0 = acc[i][j], v1 = acc[i][j + 1];
            if (c < CC) {
                // q part: only rows >= S are live queries
                if (r >= SS) {
                    const int h = c >> 6, d = c & 63, e = (c & 63) >> 1;
                    float inv = powf(10000.0f, -(float)e * (1.0f / 32.0f));
                    float ang = (float)r * inv;
                    float sn, cs;
                    sincosf(ang, &sn, &cs);
                    size_t base = (((size_t)b * HH + h) * TT + (r - SS)) * HD + d;
                    Q[base]     = v0 * cs - v1 * sn;
                    Q[base + 1] = v0 * sn + v1 * cs;
                }
            } else if (c < 2 * CC) {
                const int cc2 = c - CC;
                const int h = cc2 >> 6, d = cc2 & 63, e = (cc2 & 63) >> 1;
                float inv = powf(10000.0f, -(float)e * (1.0f / 32.0f));
                float ang = (float)r * inv;
                float sn, cs;
                sincosf(ang, &sn, &cs);
                size_t base = (((size_t)b * HH + h) * MM + (LL + r)) * HD + d;
                K[base]     = v0 * cs - v1 * sn;
                K[base + 1] = v0 * sn + v1 * cs;
            } else {
                const int cc2 = c - 2 * CC;
                const int h = cc2 >> 6, d = cc2 & 63;
                size_t base = (((size_t)b * HH + h) * MM + (LL + r)) * HD + d;
                V[base]     = v0;
                V[base + 1] = v1;
            }
        }
    }
}

// ---------------------------------------------------------------------------
// Kernel 2: prepend long_k/long_v: [B,L,H,HD] -> K/V[b][h][0..L)[d]
// ---------------------------------------------------------------------------
__global__ __launch_bounds__(256)
void copy_longkv_kernel(const float* __restrict__ lk, const float* __restrict__ lv,
                        float* __restrict__ K, float* __restrict__ V)
{
    const size_t i = (size_t)blockIdx.x * 256 + threadIdx.x;  // < B*L*H*HD = 2097152
    const int d = (int)(i & 63);
    const int h = (int)((i >> 6) & (HH - 1));
    const int j = (int)((i >> 10) & (LL - 1));
    const int b = (int)(i >> 20);
    const size_t dst = (((size_t)b * HH + h) * MM + j) * HD + d;
    K[dst] = lk[i];
    V[dst] = lv[i];
}

// ---------------------------------------------------------------------------
// Kernel 3: flash-style causal attention for query rows [L+S, M).
// Q-tile 32, K-tile 64, 256 threads. Thread (tx,ty): 2 queries x 4 keys /
// 2 queries x 4 dims. Online softmax state in LDS (rows owned by tid<32).
// ---------------------------------------------------------------------------
#define QT 32
#define KTI 64
__global__ __launch_bounds__(256)
void attn_kernel(const float* __restrict__ Q, const float* __restrict__ K,
                 const float* __restrict__ V, float* __restrict__ Yatt)
{
    __shared__ float Qt[QT][68];
    __shared__ float Kt[KTI][68];
    __shared__ float Vt[KTI][64];
    __shared__ float Pt[QT][68];
    __shared__ float mrow[QT], lrow[QT], arow[QT];

    const int b  = blockIdx.z;
    const int h  = blockIdx.y;
    const int q0 = blockIdx.x * QT;
    const int tid = threadIdx.x;
    const int tx = tid & 15, ty = tid >> 4;

    // Load Q tile (scaled by 1/sqrt(HD))
    {
        const int q = tid >> 3;            // 0..31
        const int d = (tid & 7) << 3;      // 0..56
        const float* src = Q + (((size_t)b * HH + h) * TT + (q0 + q)) * HD + d;
        float4 v0 = *(const float4*)(src);
        float4 v1 = *(const float4*)(src + 4);
        const float sc = 0.125f;
        Qt[q][d + 0] = v0.x * sc; Qt[q][d + 1] = v0.y * sc;
        Qt[q][d + 2] = v0.z * sc; Qt[q][d + 3] = v0.w * sc;
        Qt[q][d + 4] = v1.x * sc; Qt[q][d + 5] = v1.y * sc;
        Qt[q][d + 6] = v1.z * sc; Qt[q][d + 7] = v1.w * sc;
    }
    if (tid < QT) { mrow[tid] = -INFINITY; lrow[tid] = 0.f; }

    float o0[4] = {0.f, 0.f, 0.f, 0.f};
    float o1[4] = {0.f, 0.f, 0.f, 0.f};

    const int igmax  = LL + SS + q0 + QT - 1;
    const int ntiles = (igmax + KTI) / KTI;   // ceil((igmax+1)/64)

    for (int t = 0; t < ntiles; t++) {
        const int j0 = t * KTI;
        __syncthreads();   // previous PV done before overwriting K/V tiles
        {
            const int j = tid >> 2;            // 0..63
            const int d = (tid & 3) << 4;      // 0,16,32,48
            const float* ksrc = K + (((size_t)b * HH + h) * MM + (j0 + j)) * HD + d;
            const float* vsrc = V + (((size_t)b * HH + h) * MM + (j0 + j)) * HD + d;
            #pragma unroll
            for (int u = 0; u < 4; u++) {
                *(float4*)&Kt[j][d + 4 * u] = *(const float4*)(ksrc + 4 * u);
                *(float4*)&Vt[j][d + 4 * u] = *(const float4*)(vsrc + 4 * u);
            }
        }
        __syncthreads();

        // S = (Q*scale) . K^T
        float s0[4] = {0.f, 0.f, 0.f, 0.f};
        float s1[4] = {0.f, 0.f, 0.f, 0.f};
        #pragma unroll
        for (int kk = 0; kk < HD; kk += 4) {
            float4 qa = *(float4*)&Qt[2 * ty + 0][kk];
            float4 qb = *(float4*)&Qt[2 * ty + 1][kk];
            #pragma unroll
            for (int u = 0; u < 4; u++) {
                float4 kv = *(float4*)&Kt[4 * tx + u][kk];
                s0[u] = fmaf(qa.x, kv.x, s0[u]); s0[u] = fmaf(qa.y, kv.y, s0[u]);
                s0[u] = fmaf(qa.z, kv.z, s0[u]); s0[u] = fmaf(qa.w, kv.w, s0[u]);
                s1[u] = fmaf(qb.x, kv.x, s1[u]); s1[u] = fmaf(qb.y, kv.y, s1[u]);
                s1[u] = fmaf(qb.z, kv.z, s1[u]); s1[u] = fmaf(qb.w, kv.w, s1[u]);
            }
        }
        // causal mask (only the trailing tiles can clip)
        if (j0 + KTI - 1 > LL + SS + q0) {
            const int ig0 = LL + SS + q0 + 2 * ty;
            #pragma unroll
            for (int u = 0; u < 4; u++) {
                const int jg = j0 + 4 * tx + u;
                if (jg > ig0)     s0[u] = -INFINITY;
                if (jg > ig0 + 1) s1[u] = -INFINITY;
            }
        }
        *(float4*)&Pt[2 * ty + 0][4 * tx] = make_float4(s0[0], s0[1], s0[2], s0[3]);
        *(float4*)&Pt[2 * ty + 1][4 * tx] = make_float4(s1[0], s1[1], s1[2], s1[3]);
        __syncthreads();

        // Online-softmax row stats; rotated scan -> conflict-free
        if (tid < QT) {
            const int r = tid;
            const float mold = mrow[r];
            float tmax = -INFINITY;
            #pragma unroll 8
            for (int jj = 0; jj < KTI; jj++)
                tmax = fmaxf(tmax, Pt[r][(jj + r) & (KTI - 1)]);
            const float mnew  = fmaxf(mold, tmax);
            const float alpha = __expf(mold - mnew);
            float sum = 0.f;
            #pragma unroll 8
            for (int jj = 0; jj < KTI; jj++) {
                const int idx = (jj + r) & (KTI - 1);
                const float p = __expf(Pt[r][idx] - mnew);
                Pt[r][idx] = p;
                sum += p;
            }
            mrow[r] = mnew;
            lrow[r] = fmaf(lrow[r], alpha, sum);
            arow[r] = alpha;
        }
        __syncthreads();

        // O = O*alpha + P.V
        const float a0 = arow[2 * ty], a1 = arow[2 * ty + 1];
        #pragma unroll
        for (int u = 0; u < 4; u++) { o0[u] *= a0; o1[u] *= a1; }
        #pragma unroll
        for (int jj = 0; jj < KTI; jj += 4) {
            float4 p0 = *(float4*)&Pt[2 * ty + 0][jj];
            float4 p1 = *(float4*)&Pt[2 * ty + 1][jj];
            float pa[4] = {p0.x, p0.y, p0.z, p0.w};
            float pb[4] = {p1.x, p1.y, p1.z, p1.w};
            #pragma unroll
            for (int u = 0; u < 4; u++) {
                float4 vv = *(float4*)&Vt[jj + u][4 * tx];
                o0[0] = fmaf(pa[u], vv.x, o0[0]); o0[1] = fmaf(pa[u], vv.y, o0[1]);
                o0[2] = fmaf(pa[u], vv.z, o0[2]); o0[3] = fmaf(pa[u], vv.w, o0[3]);
                o1[0] = fmaf(pb[u], vv.x, o1[0]); o1[1] = fmaf(pb[u], vv.y, o1[1]);
                o1[2] = fmaf(pb[u], vv.z, o1[2]); o1[3] = fmaf(pb[u], vv.w, o1[3]);
            }
        }
    }

    // normalize + store: Yatt[b][q0+q][h*64 + 4tx..]
    const float li0 = 1.0f / lrow[2 * ty + 0];
    const float li1 = 1.0f / lrow[2 * ty + 1];
    size_t ob = ((size_t)b * TT + (q0 + 2 * ty)) * CC + h * HD + 4 * tx;
    *(float4*)(Yatt + ob)      = make_float4(o0[0] * li0, o0[1] * li0, o0[2] * li0, o0[3] * li0);
    *(float4*)(Yatt + ob + CC) = make_float4(o1[0] * li1, o1[1] * li1, o1[2] * li1, o1[3] * li1);
}

// ---------------------------------------------------------------------------
// Kernel 4: out = Yatt @ w_proj   (2048 x 1024 x 1024)
// ---------------------------------------------------------------------------
__global__ __launch_bounds__(256)
void proj_kernel(const float* __restrict__ Y, const float* __restrict__ W,
                 float* __restrict__ out)
{
    __shared__ float As[16][68];
    __shared__ float Bs[16][68];
    const int row0 = blockIdx.y * 64;   // in [0, 2048)
    const int col0 = blockIdx.x * 64;   // in [0, 1024)
    const int tid = threadIdx.x;
    const int tx = tid & 15, ty = tid >> 4;

    const int ar = tid >> 2;
    const int ak = (tid & 3) << 2;
    const int bk = tid >> 4;
    const int bn = (tid & 15) << 2;

    const float* arow = Y + (size_t)(row0 + ar) * CC;

    float acc[4][4];
    #pragma unroll
    for (int i = 0; i < 4; i++)
        #pragma unroll
        for (int j = 0; j < 4; j++) acc[i][j] = 0.f;

    for (int k0 = 0; k0 < CC; k0 += 16) {
        float4 av = *(const float4*)(arow + k0 + ak);
        float4 bv = *(const float4*)(W + (size_t)(k0 + bk) * CC + col0 + bn);
        __syncthreads();
        As[ak + 0][ar] = av.x;
        As[ak + 1][ar] = av.y;
        As[ak + 2][ar] = av.z;
        As[ak + 3][ar] = av.w;
        *(float4*)&Bs[bk][bn] = bv;
        __syncthreads();
        #pragma unroll
        for (int kk = 0; kk < 16; kk++) {
            float4 a4 = *(float4*)&As[kk][ty * 4];
            float4 b4 = *(float4*)&Bs[kk][tx * 4];
            float aa[4] = {a4.x, a4.y, a4.z, a4.w};
            float bbv[4] = {b4.x, b4.y, b4.z, b4.w};
            #pragma unroll
            for (int i = 0; i < 4; i++)
                #pragma unroll
                for (int j = 0; j < 4; j++)
                    acc[i][j] = fmaf(aa[i], bbv[j], acc[i][j]);
        }
    }
    #pragma unroll
    for (int i = 0; i < 4; i++) {
        size_t ob = (size_t)(row0 + ty * 4 + i) * CC + col0 + tx * 4;
        *(float4*)(out + ob) = make_float4(acc[i][0], acc[i][1], acc[i][2], acc[i][3]);
    }
}

// ---------------------------------------------------------------------------
extern "C" void kernel_launch(void* const* d_in, const int* in_sizes, int n_in,
                              void* d_out, int out_size, void* d_ws, size_t ws_size,
                              hipStream_t stream)
{
    (void)in_sizes; (void)n_in; (void)out_size; (void)ws_size;
    const float* x      = (const float*)d_in[0];
    const float* stm    = (const float*)d_in[1];
    // d_in[2] = long_q: provably unused (output slice only covers query rows >= L+S)
    const float* long_k = (const float*)d_in[3];
    const float* long_v = (const float*)d_in[4];
    const float* w_attn = (const float*)d_in[5];
    const float* w_proj = (const float*)d_in[6];
    float* out = (float*)d_out;

    float* Q    = (float*)d_ws;                       // B*H*T*HD   = 2,097,152 f
    float* K    = Q + (size_t)BB * HH * TT * HD;      // B*H*M*HD   = 5,242,880 f
    float* V    = K + (size_t)BB * HH * MM * HD;
    float* Yatt = V + (size_t)BB * HH * MM * HD;      // B*T*C      = 2,097,152 f
    // total ws use: 56 MB

    dim3 g1(C3 / 64, ST / 64, BB);     // 48 x 24 x 2
    qkv_rope_kernel<<<g1, 256, 0, stream>>>(x, stm, w_attn, Q, K, V);

    copy_longkv_kernel<<<(BB * LL * HH * HD) / 256, 256, 0, stream>>>(long_k, long_v, K, V);

    dim3 g2(TT / QT, HH, BB);          // 32 x 16 x 2
    attn_kernel<<<g2, 256, 0, stream>>>(Q, K, V, Yatt);

    dim3 g3(CC / 64, (BB * TT) / 64, 1);   // 16 x 32
    proj_kernel<<<g3, 256, 0, stream>>>(Yatt, w_proj, out);
}

// Round 2
// 787.387 us; speedup vs baseline: 3.3811x; 3.3811x over previous
//
#include <hip/hip_runtime.h>
#include <math.h>

// Problem constants
#define BB 2
#define TT 1024
#define CC 1024
#define HH 16
#define HD 64
#define SS 512
#define LL 1024
#define ST 1536   // S+T
#define MM 2560   // L+S+T
#define C3 3072   // 3*C

// ---------------------------------------------------------------------------
// Kernel 1: qkv = xcat @ w_attn, fused RoPE, scatter to Q/K/V in [B,H,seq,HD]
// (unchanged from round 1 — not the bottleneck this round)
// ---------------------------------------------------------------------------
__global__ __launch_bounds__(256)
void qkv_rope_kernel(const float* __restrict__ x, const float* __restrict__ stm,
                     const float* __restrict__ w_attn,
                     float* __restrict__ Q, float* __restrict__ K, float* __restrict__ V)
{
    __shared__ float As[16][68];   // A transposed: As[k][m]
    __shared__ float Bs[16][68];   // Bs[k][n]
    const int b    = blockIdx.z;
    const int row0 = blockIdx.y * 64;   // row in xcat [0,1536)
    const int col0 = blockIdx.x * 64;   // col in [0,3072)
    const int tid  = threadIdx.x;
    const int tx = tid & 15, ty = tid >> 4;

    const int ar = tid >> 2;          // 0..63  (tile row)
    const int ak = (tid & 3) << 2;    // 0,4,8,12
    const int bk = tid >> 4;          // 0..15  (k row)
    const int bn = (tid & 15) << 2;   // 0..60

    const int r_a = row0 + ar;
    const float* arow = (r_a < SS) ? (stm + ((size_t)b * SS + r_a) * CC)
                                   : (x   + ((size_t)b * TT + (r_a - SS)) * CC);

    float acc[4][4];
    #pragma unroll
    for (int i = 0; i < 4; i++)
        #pragma unroll
        for (int j = 0; j < 4; j++) acc[i][j] = 0.f;

    for (int k0 = 0; k0 < CC; k0 += 16) {
        float4 av = *(const float4*)(arow + k0 + ak);
        float4 bv = *(const float4*)(w_attn + (size_t)(k0 + bk) * C3 + col0 + bn);
        __syncthreads();
        As[ak + 0][ar] = av.x;
        As[ak + 1][ar] = av.y;
        As[ak + 2][ar] = av.z;
        As[ak + 3][ar] = av.w;
        *(float4*)&Bs[bk][bn] = bv;
        __syncthreads();
        #pragma unroll
        for (int kk = 0; kk < 16; kk++) {
            float4 a4 = *(float4*)&As[kk][ty * 4];
            float4 b4 = *(float4*)&Bs[kk][tx * 4];
            float aa[4] = {a4.x, a4.y, a4.z, a4.w};
            float bbv[4] = {b4.x, b4.y, b4.z, b4.w};
            #pragma unroll
            for (int i = 0; i < 4; i++)
                #pragma unroll
                for (int j = 0; j < 4; j++)
                    acc[i][j] = fmaf(aa[i], bbv[j], acc[i][j]);
        }
    }

    #pragma unroll
    for (int i = 0; i < 4; i++) {
        const int r = row0 + ty * 4 + i;
        #pragma unroll
        for (int j = 0; j < 4; j += 2) {
            const int c = col0 + tx * 4 + j;
            float v0 = acc[i][j], v1 = acc[i][j + 1];
            if (c < CC) {
                if (r >= SS) {
                    const int h = c >> 6, d = c & 63, e = (c & 63) >> 1;
                    float inv = powf(10000.0f, -(float)e * (1.0f / 32.0f));
                    float ang = (float)r * inv;
                    float sn, cs;
                    sincosf(ang, &sn, &cs);
                    size_t base = (((size_t)b * HH + h) * TT + (r - SS)) * HD + d;
                    Q[base]     = v0 * cs - v1 * sn;
                    Q[base + 1] = v0 * sn + v1 * cs;
                }
            } else if (c < 2 * CC) {
                const int cc2 = c - CC;
                const int h = cc2 >> 6, d = cc2 & 63, e = (cc2 & 63) >> 1;
                float inv = powf(10000.0f, -(float)e * (1.0f / 32.0f));
                float ang = (float)r * inv;
                float sn, cs;
                sincosf(ang, &sn, &cs);
                size_t base = (((size_t)b * HH + h) * MM + (LL + r)) * HD + d;
                K[base]     = v0 * cs - v1 * sn;
                K[base + 1] = v0 * sn + v1 * cs;
            } else {
                const int cc2 = c - 2 * CC;
                const int h = cc2 >> 6, d = cc2 & 63;
                size_t base = (((size_t)b * HH + h) * MM + (LL + r)) * HD + d;
                V[base]     = v0;
                V[base + 1] = v1;
            }
        }
    }
}

// ---------------------------------------------------------------------------
// Kernel 2: prepend long_k/long_v
// ---------------------------------------------------------------------------
__global__ __launch_bounds__(256)
void copy_longkv_kernel(const float* __restrict__ lk, const float* __restrict__ lv,
                        float* __restrict__ K, float* __restrict__ V)
{
    const size_t i = (size_t)blockIdx.x * 256 + threadIdx.x;
    const int d = (int)(i & 63);
    const int h = (int)((i >> 6) & (HH - 1));
    const int j = (int)((i >> 10) & (LL - 1));
    const int b = (int)(i >> 20);
    const size_t dst = (((size_t)b * HH + h) * MM + j) * HD + d;
    K[dst] = lk[i];
    V[dst] = lv[i];
}

// ---------------------------------------------------------------------------
// Kernel 3: flash attention, rebuilt for conflict-free LDS.
//   64 q x 64 k tile, 256 threads, 4q x 4k per thread (tx=keys, ty=queries).
//   Q,K,P stored TRANSPOSED in LDS (dim/key-major) with column swizzle
//   col = (idx + 4*(row>>2)) & 63 -> all compute reads row-uniform, <=2-way.
//   Softmax stats in registers, shfl_xor across the 16-lane row group.
//   P write->read is wave-private rows; same-wave LDS is in-order, pinned
//   with s_waitcnt lgkmcnt(0). Only 2 __syncthreads per K-tile.
// ---------------------------------------------------------------------------
#define QT 64
#define KTI 64
__global__ __launch_bounds__(256)
void attn_kernel(const float* __restrict__ Q, const float* __restrict__ K,
                 const float* __restrict__ V, float* __restrict__ Yatt)
{
    __shared__ float QtT[64][64];   // [dim][q]  swizzled
    __shared__ float KtT[64][64];   // [dim][key] swizzled
    __shared__ float Vt [64][64];   // [key][dim] swizzled
    __shared__ float PtT[64][64];   // [key][q]  swizzled
    // total = 64 KiB exactly

    const int hb = blockIdx.x;           // 0..31
    const int h  = hb & 15;
    const int b  = hb >> 4;
    const int q0 = blockIdx.y * QT;
    const int tid = threadIdx.x;
    const int tx = tid & 15;             // key group: keys 4tx..4tx+3
    const int ty = tid >> 4;             // query group: q 4ty..4ty+3

    // ---- stage Q (transposed, swizzled, pre-scaled by 1/sqrt(HD)) ----
    {
        const int qr = tid >> 2;             // 0..63
        const int d0 = (tid & 3) << 4;       // 0,16,32,48
        const float* qb = Q + (((size_t)b * HH + h) * TT + q0 + qr) * HD + d0;
        #pragma unroll
        for (int u = 0; u < 4; u++) {
            float4 q4 = *(const float4*)(qb + 4 * u);
            const int col = (qr + d0 + 4 * u) & 63;
            QtT[d0 + 4 * u + 0][col] = q4.x * 0.125f;
            QtT[d0 + 4 * u + 1][col] = q4.y * 0.125f;
            QtT[d0 + 4 * u + 2][col] = q4.z * 0.125f;
            QtT[d0 + 4 * u + 3][col] = q4.w * 0.125f;
        }
    }

    float m[4], l[4], o[4][4];
    #pragma unroll
    for (int i = 0; i < 4; i++) {
        m[i] = -INFINITY; l[i] = 0.f;
        #pragma unroll
        for (int u = 0; u < 4; u++) o[i][u] = 0.f;
    }

    const int qg_min  = LL + SS + q0;
    const int ntiles  = qg_min / KTI + 1;     // covers keys 0 .. qg_min+63

    for (int t = 0; t < ntiles; t++) {
        const int j0 = t * KTI;
        __syncthreads();   // everyone done reading KtT/Vt from previous tile
        {
            const int jr = tid >> 2;             // 0..63
            const int d0 = (tid & 3) << 4;
            const size_t rb = ((size_t)b * HH + h) * MM + j0 + jr;
            const float* kb = K + rb * HD + d0;
            const float* vb = V + rb * HD + d0;
            #pragma unroll
            for (int u = 0; u < 4; u++) {
                float4 k4 = *(const float4*)(kb + 4 * u);
                float4 v4 = *(const float4*)(vb + 4 * u);
                const int kcol = (jr + d0 + 4 * u) & 63;
                KtT[d0 + 4 * u + 0][kcol] = k4.x;
                KtT[d0 + 4 * u + 1][kcol] = k4.y;
                KtT[d0 + 4 * u + 2][kcol] = k4.z;
                KtT[d0 + 4 * u + 3][kcol] = k4.w;
                *(float4*)&Vt[jr][(d0 + 4 * u + ((jr >> 2) << 2)) & 63] = v4;
            }
        }
        __syncthreads();

        // ---- S = Q.K^T : s[i][u], q=4ty+i, key=4tx+u ----
        float s[4][4];
        #pragma unroll
        for (int i = 0; i < 4; i++)
            #pragma unroll
            for (int u = 0; u < 4; u++) s[i][u] = 0.f;

        #pragma unroll
        for (int k4 = 0; k4 < 16; k4++) {
            const int qcol = (4 * ty + 4 * k4) & 63;
            const int kcol = (4 * tx + 4 * k4) & 63;
            #pragma unroll
            for (int w = 0; w < 4; w++) {
                float4 qv = *(float4*)&QtT[4 * k4 + w][qcol];   // comps = q idx i
                float4 kv = *(float4*)&KtT[4 * k4 + w][kcol];   // comps = key idx u
                float qq[4] = {qv.x, qv.y, qv.z, qv.w};
                float kk[4] = {kv.x, kv.y, kv.z, kv.w};
                #pragma unroll
                for (int i = 0; i < 4; i++)
                    #pragma unroll
                    for (int u = 0; u < 4; u++)
                        s[i][u] = fmaf(qq[i], kk[u], s[i][u]);
            }
        }

        // ---- causal mask (only diagonal-clipping tiles) ----
        if (j0 + KTI - 1 > qg_min) {
            #pragma unroll
            for (int i = 0; i < 4; i++) {
                const int qg = qg_min + 4 * ty + i;
                #pragma unroll
                for (int u = 0; u < 4; u++)
                    if (j0 + 4 * tx + u > qg) s[i][u] = -INFINITY;
            }
        }

        // ---- online softmax: register stats + shfl_xor over 16-lane row group ----
        float p[4][4];
        float alpha[4];
        #pragma unroll
        for (int i = 0; i < 4; i++) {
            float tmax = fmaxf(fmaxf(s[i][0], s[i][1]), fmaxf(s[i][2], s[i][3]));
            tmax = fmaxf(tmax, __shfl_xor(tmax, 1));
            tmax = fmaxf(tmax, __shfl_xor(tmax, 2));
            tmax = fmaxf(tmax, __shfl_xor(tmax, 4));
            tmax = fmaxf(tmax, __shfl_xor(tmax, 8));
            const float mnew = fmaxf(m[i], tmax);
            alpha[i] = __expf(m[i] - mnew);
            float sum = 0.f;
            #pragma unroll
            for (int u = 0; u < 4; u++) {
                p[i][u] = __expf(s[i][u] - mnew);
                sum += p[i][u];
            }
            sum += __shfl_xor(sum, 1);
            sum += __shfl_xor(sum, 2);
            sum += __shfl_xor(sum, 4);
            sum += __shfl_xor(sum, 8);
            l[i] = fmaf(l[i], alpha[i], sum);
            m[i] = mnew;
        }

        // ---- write P transposed (wave-private rows) ----
        const int pcol = (4 * ty + 4 * tx) & 63;
        #pragma unroll
        for (int u = 0; u < 4; u++)
            *(float4*)&PtT[4 * tx + u][pcol] =
                make_float4(p[0][u], p[1][u], p[2][u], p[3][u]);

        // same-wave LDS write->read: drain our ds ops, block compiler motion
        __builtin_amdgcn_s_waitcnt(0xc07f);   // lgkmcnt(0)
        __builtin_amdgcn_wave_barrier();

        // ---- O = O*alpha + P.V ----
        #pragma unroll
        for (int i = 0; i < 4; i++)
            #pragma unroll
            for (int u = 0; u < 4; u++) o[i][u] *= alpha[i];

        #pragma unroll
        for (int j4 = 0; j4 < 16; j4++) {
            const int pc = (4 * ty + 4 * j4) & 63;
            const int vc = (4 * tx + 4 * j4) & 63;
            #pragma unroll
            for (int w = 0; w < 4; w++) {
                float4 pv = *(float4*)&PtT[4 * j4 + w][pc];   // comps = q idx i
                float4 vv = *(float4*)&Vt [4 * j4 + w][vc];   // comps = dim idx u
                float pp[4] = {pv.x, pv.y, pv.z, pv.w};
                float vva[4] = {vv.x, vv.y, vv.z, vv.w};
                #pragma unroll
                for (int i = 0; i < 4; i++)
                    #pragma unroll
                    for (int u = 0; u < 4; u++)
                        o[i][u] = fmaf(pp[i], vva[u], o[i][u]);
            }
        }
    }

    // ---- normalize + store ----
    #pragma unroll
    for (int i = 0; i < 4; i++) {
        const float inv = 1.0f / l[i];
        size_t ob = ((size_t)b * TT + (q0 + 4 * ty + i)) * CC + h * HD + 4 * tx;
        *(float4*)(Yatt + ob) =
            make_float4(o[i][0] * inv, o[i][1] * inv, o[i][2] * inv, o[i][3] * inv);
    }
}

// ---------------------------------------------------------------------------
// Kernel 4: out = Yatt @ w_proj (unchanged)
// ---------------------------------------------------------------------------
__global__ __launch_bounds__(256)
void proj_kernel(const float* __restrict__ Y, const float* __restrict__ W,
                 float* __restrict__ out)
{
    __shared__ float As[16][68];
    __shared__ float Bs[16][68];
    const int row0 = blockIdx.y * 64;
    const int col0 = blockIdx.x * 64;
    const int tid = threadIdx.x;
    const int tx = tid & 15, ty = tid >> 4;

    const int ar = tid >> 2;
    const int ak = (tid & 3) << 2;
    const int bk = tid >> 4;
    const int bn = (tid & 15) << 2;

    const float* arow = Y + (size_t)(row0 + ar) * CC;

    float acc[4][4];
    #pragma unroll
    for (int i = 0; i < 4; i++)
        #pragma unroll
        for (int j = 0; j < 4; j++) acc[i][j] = 0.f;

    for (int k0 = 0; k0 < CC; k0 += 16) {
        float4 av = *(const float4*)(arow + k0 + ak);
        float4 bv = *(const float4*)(W + (size_t)(k0 + bk) * CC + col0 + bn);
        __syncthreads();
        As[ak + 0][ar] = av.x;
        As[ak + 1][ar] = av.y;
        As[ak + 2][ar] = av.z;
        As[ak + 3][ar] = av.w;
        *(float4*)&Bs[bk][bn] = bv;
        __syncthreads();
        #pragma unroll
        for (int kk = 0; kk < 16; kk++) {
            float4 a4 = *(float4*)&As[kk][ty * 4];
            float4 b4 = *(float4*)&Bs[kk][tx * 4];
            float aa[4] = {a4.x, a4.y, a4.z, a4.w};
            float bbv[4] = {b4.x, b4.y, b4.z, b4.w};
            #pragma unroll
            for (int i = 0; i < 4; i++)
                #pragma unroll
                for (int j = 0; j < 4; j++)
                    acc[i][j] = fmaf(aa[i], bbv[j], acc[i][j]);
        }
    }
    #pragma unroll
    for (int i = 0; i < 4; i++) {
        size_t ob = (size_t)(row0 + ty * 4 + i) * CC + col0 + tx * 4;
        *(float4*)(out + ob) = make_float4(acc[i][0], acc[i][1], acc[i][2], acc[i][3]);
    }
}

// ---------------------------------------------------------------------------
extern "C" void kernel_launch(void* const* d_in, const int* in_sizes, int n_in,
                              void* d_out, int out_size, void* d_ws, size_t ws_size,
                              hipStream_t stream)
{
    (void)in_sizes; (void)n_in; (void)out_size; (void)ws_size;
    const float* x      = (const float*)d_in[0];
    const float* stm    = (const float*)d_in[1];
    // d_in[2] = long_q: unused (output slice only covers query rows >= L+S)
    const float* long_k = (const float*)d_in[3];
    const float* long_v = (const float*)d_in[4];
    const float* w_attn = (const float*)d_in[5];
    const float* w_proj = (const float*)d_in[6];
    float* out = (float*)d_out;

    float* Q    = (float*)d_ws;
    float* K    = Q + (size_t)BB * HH * TT * HD;
    float* V    = K + (size_t)BB * HH * MM * HD;
    float* Yatt = V + (size_t)BB * HH * MM * HD;

    dim3 g1(C3 / 64, ST / 64, BB);
    qkv_rope_kernel<<<g1, 256, 0, stream>>>(x, stm, w_attn, Q, K, V);

    copy_longkv_kernel<<<(BB * LL * HH * HD) / 256, 256, 0, stream>>>(long_k, long_v, K, V);

    dim3 g2(HH * BB, TT / QT);     // 32 x 16 blocks, 2 per CU
    attn_kernel<<<g2, 256, 0, stream>>>(Q, K, V, Yatt);

    dim3 g3(CC / 64, (BB * TT) / 64, 1);
    proj_kernel<<<g3, 256, 0, stream>>>(Yatt, w_proj, out);
}

// Round 3
// 437.925 us; speedup vs baseline: 6.0793x; 1.7980x over previous
//
#include <hip/hip_runtime.h>
#include <math.h>

// Problem constants
#define BB 2
#define TT 1024
#define CC 1024
#define HH 16
#define HD 64
#define SS 512
#define LL 1024
#define ST 1536   // S+T
#define MM 2560   // L+S+T
#define C3 3072   // 3*C

typedef __attribute__((ext_vector_type(8))) short short8;    // 8 bf16 (4 VGPRs)
typedef __attribute__((ext_vector_type(4))) short short4v;
typedef __attribute__((ext_vector_type(4))) float floatx4;

__device__ __forceinline__ unsigned short f2bf(float f) {
    union { float f; unsigned u; } v; v.f = f;
    unsigned r = v.u + 0x7fffu + ((v.u >> 16) & 1u);   // RNE
    return (unsigned short)(r >> 16);
}

// ---------------------------------------------------------------------------
// Prep 1: xcat -> bf16 [B][1536][1024]
// ---------------------------------------------------------------------------
__global__ __launch_bounds__(256)
void cast_xcat(const float* __restrict__ x, const float* __restrict__ stm,
               short* __restrict__ Xb)
{
    const int idx = blockIdx.x * 256 + threadIdx.x;   // one float4 each
    const int rg  = idx >> 8;                         // 0..3071
    const int c   = (idx & 255) << 2;
    const int b   = rg >= ST;
    const int r   = rg - b * ST;
    const float* src = (r < SS) ? (stm + ((size_t)b * SS + r) * CC + c)
                                : (x   + ((size_t)b * TT + (r - SS)) * CC + c);
    float4 v = *(const float4*)src;
    short4v o;
    o.x = (short)f2bf(v.x); o.y = (short)f2bf(v.y);
    o.z = (short)f2bf(v.z); o.w = (short)f2bf(v.w);
    *(short4v*)(Xb + (size_t)rg * CC + c) = o;
}

// ---------------------------------------------------------------------------
// Prep 2: transpose+cast weight [K][N] fp32 -> [N][K] bf16
// ---------------------------------------------------------------------------
__global__ __launch_bounds__(256)
void wtrans(const float* __restrict__ W, short* __restrict__ WT, int Kd, int Nd)
{
    __shared__ float Tl[32][33];
    const int n0 = blockIdx.x * 32, k0 = blockIdx.y * 32;
    const int t = threadIdx.x;
    const int r = t >> 3, c4 = (t & 7) << 2;
    float4 v = *(const float4*)(W + (size_t)(k0 + r) * Nd + n0 + c4);
    Tl[r][c4 + 0] = v.x; Tl[r][c4 + 1] = v.y;
    Tl[r][c4 + 2] = v.z; Tl[r][c4 + 3] = v.w;
    __syncthreads();
    short4v o;
    o.x = (short)f2bf(Tl[c4 + 0][r]); o.y = (short)f2bf(Tl[c4 + 1][r]);
    o.z = (short)f2bf(Tl[c4 + 2][r]); o.w = (short)f2bf(Tl[c4 + 3][r]);
    *(short4v*)(WT + (size_t)(n0 + r) * Kd + k0 + c4) = o;
}

// ---------------------------------------------------------------------------
// Prep 3: long_k/long_v [B][L][H][64] fp32 -> K rows [0,L) bf16, Vtmp same
// ---------------------------------------------------------------------------
__global__ __launch_bounds__(256)
void copy_longkv(const float* __restrict__ lk, const float* __restrict__ lv,
                 short* __restrict__ Kg, short* __restrict__ Vtmp)
{
    const int idx = blockIdx.x * 256 + threadIdx.x;   // per 4 elems, 524288 total
    const int d4 = (idx & 15) << 2;
    const int h  = (idx >> 4) & 15;
    const int j  = (idx >> 8) & 1023;
    const int b  = idx >> 18;
    const size_t si = (((size_t)b * LL + j) * HH + h) * HD + d4;
    float4 kv = *(const float4*)(lk + si);
    float4 vv = *(const float4*)(lv + si);
    short4v ko, vo;
    ko.x = (short)f2bf(kv.x); ko.y = (short)f2bf(kv.y);
    ko.z = (short)f2bf(kv.z); ko.w = (short)f2bf(kv.w);
    vo.x = (short)f2bf(vv.x); vo.y = (short)f2bf(vv.y);
    vo.z = (short)f2bf(vv.z); vo.w = (short)f2bf(vv.w);
    const size_t di = (((size_t)b * HH + h) * MM + j) * HD + d4;
    *(short4v*)(Kg + di) = ko;
    *(short4v*)(Vtmp + di) = vo;
}

// ---------------------------------------------------------------------------
// Prep 4: Vtmp [bh][2560][64] -> Vt [bh][64][2560] (bf16 transpose)
// ---------------------------------------------------------------------------
__global__ __launch_bounds__(256)
void vtrans(const short* __restrict__ Vtmp, short* __restrict__ Vt)
{
    __shared__ short Tl[64][72];
    const int bh = blockIdx.y;
    const int j0 = blockIdx.x * 64;
    const int t = threadIdx.x;
    const int r = t >> 2, c = t & 3;
    const short* src = Vtmp + ((size_t)bh * MM + j0 + r) * HD + c * 8;
    short8 v0 = *(const short8*)(src);
    short8 v1 = *(const short8*)(src + 32);
    *(short8*)&Tl[r][c * 8] = v0;
    *(short8*)&Tl[r][c * 8 + 32] = v1;
    __syncthreads();
    short* dst = Vt + ((size_t)bh * HD + r) * MM + j0;
    short8 o0, o1;
    #pragma unroll
    for (int u = 0; u < 8; u++) {
        o0[u] = Tl[c * 8 + u][r];
        o1[u] = Tl[c * 8 + 32 + u][r];
    }
    *(short8*)(dst + c * 8) = o0;
    *(short8*)(dst + c * 8 + 32) = o1;
}

// ---------------------------------------------------------------------------
// Kernel: qkv MFMA GEMM (128x128 tile, 4 waves 2x2, 4x4 16x16x32 per wave)
// A = Xb [1536][1024] bf16, B = WaT [3072][1024] bf16 (row n = qkv col)
// Epilogue: RoPE (pair in lanes l,l^1 via shfl), scatter Q/K/Vtmp bf16.
// LDS 16B-chunk swizzle slot=(chunk+((row&15)>>1))&3 -> <=2-way everywhere.
// ---------------------------------------------------------------------------
__global__ __launch_bounds__(256)
void qkv_gemm(const short* __restrict__ A, const short* __restrict__ Bt,
              short* __restrict__ Qo, short* __restrict__ Ko, short* __restrict__ Vo)
{
    __shared__ short As[128 * 32];
    __shared__ short Bs[128 * 32];
    const int b = blockIdx.z;
    const int row0 = blockIdx.y * 128, col0 = blockIdx.x * 128;
    const int tid = threadIdx.x;
    const int w = tid >> 6, l = tid & 63, quad = l >> 4, cl = l & 15;
    const int wr = w >> 1, wc = w & 1;

    const int sr = tid >> 1, sc = (tid & 1) << 1;   // staging: row, first chunk
    const short* ga = A + ((size_t)b * ST + row0 + sr) * CC + sc * 8;
    const short* gb = Bt + (size_t)(col0 + sr) * CC + sc * 8;
    const int rot = (sr & 15) >> 1;
    const int sl0 = (sc + rot) & 3, sl1 = (sc + 1 + rot) & 3;
    const int fs = (quad + (cl >> 1)) & 3;           // fragment chunk slot

    floatx4 acc[4][4];
    #pragma unroll
    for (int mi = 0; mi < 4; mi++)
        #pragma unroll
        for (int ni = 0; ni < 4; ni++) acc[mi][ni] = (floatx4){0.f, 0.f, 0.f, 0.f};

    for (int k0 = 0; k0 < CC; k0 += 32) {
        short8 a0 = *(const short8*)(ga + k0);
        short8 a1 = *(const short8*)(ga + k0 + 8);
        short8 b0 = *(const short8*)(gb + k0);
        short8 b1 = *(const short8*)(gb + k0 + 8);
        __syncthreads();
        *(short8*)&As[sr * 32 + sl0 * 8] = a0;
        *(short8*)&As[sr * 32 + sl1 * 8] = a1;
        *(short8*)&Bs[sr * 32 + sl0 * 8] = b0;
        *(short8*)&Bs[sr * 32 + sl1 * 8] = b1;
        __syncthreads();
        short8 af[4], bf[4];
        #pragma unroll
        for (int mi = 0; mi < 4; mi++)
            af[mi] = *(const short8*)&As[(wr * 64 + mi * 16 + cl) * 32 + fs * 8];
        #pragma unroll
        for (int ni = 0; ni < 4; ni++)
            bf[ni] = *(const short8*)&Bs[(wc * 64 + ni * 16 + cl) * 32 + fs * 8];
        #pragma unroll
        for (int mi = 0; mi < 4; mi++)
            #pragma unroll
            for (int ni = 0; ni < 4; ni++)
                acc[mi][ni] = __builtin_amdgcn_mfma_f32_16x16x32_bf16(
                    af[mi], bf[ni], acc[mi][ni], 0, 0, 0);
    }

    // Epilogue: C-layout element (row = quad*4+r, col = cl) per 16x16 tile.
    const bool hasQ = (row0 >= SS);   // block-uniform
    #pragma unroll
    for (int ni = 0; ni < 4; ni++) {
        const int Cg = col0 + wc * 64 + ni * 16 + cl;   // qkv column
        const int reg = Cg >> 10;                        // 0=Q 1=K 2=V (wave-uniform)
        const int d = Cg & 63;
        const int hh = (Cg >> 6) & 15;
        float invf = 0.f;
        if (reg < 2) invf = powf(10000.0f, -(float)(d >> 1) * (1.0f / 32.0f));
        #pragma unroll
        for (int mi = 0; mi < 4; mi++) {
            #pragma unroll
            for (int r = 0; r < 4; r++) {
                const int R = row0 + wr * 64 + mi * 16 + quad * 4 + r;  // xcat row
                float v = acc[mi][ni][r];
                float out;
                if (reg < 2) {
                    float sn, cs;
                    sincosf((float)R * invf, &sn, &cs);
                    float po = __shfl_xor(v, 1);
                    out = ((cl & 1) == 0) ? (v * cs - po * sn) : (po * sn + v * cs);
                } else {
                    out = v;
                }
                unsigned short bfv = f2bf(out);
                int ob = __shfl_xor((int)bfv, 1);
                if ((cl & 1) == 0) {
                    unsigned word = (unsigned)bfv | (((unsigned)ob & 0xffffu) << 16);
                    if (reg == 0) {
                        if (hasQ)
                            *(unsigned*)(Qo + (((size_t)b * HH + hh) * TT + (R - SS)) * HD + d) = word;
                    } else if (reg == 1) {
                        *(unsigned*)(Ko + (((size_t)b * HH + hh) * MM + LL + R) * HD + d) = word;
                    } else {
                        *(unsigned*)(Vo + (((size_t)b * HH + hh) * MM + LL + R) * HD + d) = word;
                    }
                }
            }
        }
    }
}

// ---------------------------------------------------------------------------
// Kernel: MFMA flash attention. Block = 4 waves, 64 q (16/wave), K-tile 64.
// S: A=Q frag (regs), B=K tile LDS [key][d]. Online softmax in regs
// (shfl_xor over 16-lane group). P: C-layout -> LDS (wave-private, swizzled)
// -> A-layout frags. PV: B=Vt tile LDS [d][key]. 2 __syncthreads per tile.
// ---------------------------------------------------------------------------
__global__ __launch_bounds__(256)
void attn_mfma(const short* __restrict__ Qg, const short* __restrict__ Kg,
               const short* __restrict__ Vt, short* __restrict__ Yatt)
{
    __shared__ short Ks[64 * 64];     // [key][d]  chunk-swizzled
    __shared__ short Vs[64 * 64];     // [d][key]  chunk-swizzled
    __shared__ short Ps[4 * 16 * 64]; // per-wave [q][key] chunk-swizzled

    const int bh = blockIdx.x, b = bh >> 4, h = bh & 15;
    const int q0 = (15 - blockIdx.y) * 64;   // reversed: heavy blocks dispatch first
    const int tid = threadIdx.x, w = tid >> 6, l = tid & 63;
    const int quad = l >> 4, cl = l & 15;

    // Q fragments: lane holds Q[q = w*16+cl][d = quad*8 .. +8 (+32)]
    const short* qptr = Qg + ((size_t)bh * TT + q0 + w * 16 + cl) * HD + quad * 8;
    short8 qa0 = *(const short8*)qptr;
    short8 qa1 = *(const short8*)(qptr + 32);

    floatx4 o[4];
    float m_[4], l_[4];
    #pragma unroll
    for (int r = 0; r < 4; r++) {
        m_[r] = -INFINITY; l_[r] = 0.f;
        o[r] = (floatx4){0.f, 0.f, 0.f, 0.f};   // o[nt] reused; init all 4
    }

    const int sr = tid >> 2, sc = tid & 3;       // staging row, chunk
    const int srot = (sr & 15) >> 1;
    const int ss0 = (sc + srot) & 7, ss1 = (sc + 4 + srot) & 7;
    const short* kgb = Kg + (size_t)bh * MM * HD;
    const short* vgb = Vt + ((size_t)bh * HD + sr) * MM;

    const int fsA = (quad + (cl >> 1)) & 7;      // K/V frag slots (kh0 / kh1)
    const int fsB = (quad + 4 + (cl >> 1)) & 7;
    const int psA = (quad + cl) & 7;             // P frag slots
    const int psB = (quad + 4 + cl) & 7;

    const int qg_base = LL + SS + q0 + w * 16;   // + quad*4 + r = global q row
    const int ntiles = (LL + SS + q0) / 64 + 1;

    for (int t = 0; t < ntiles; t++) {
        const int j0 = t * 64;
        __syncthreads();
        {
            const short* ks_ = kgb + (size_t)(j0 + sr) * HD + sc * 8;
            short8 k0v = *(const short8*)ks_;
            short8 k1v = *(const short8*)(ks_ + 32);
            const short* vs_ = vgb + j0 + sc * 8;
            short8 v0v = *(const short8*)vs_;
            short8 v1v = *(const short8*)(vs_ + 32);
            *(short8*)&Ks[sr * 64 + ss0 * 8] = k0v;
            *(short8*)&Ks[sr * 64 + ss1 * 8] = k1v;
            *(short8*)&Vs[sr * 64 + ss0 * 8] = v0v;
            *(short8*)&Vs[sr * 64 + ss1 * 8] = v1v;
        }
        __syncthreads();

        // ---- S = Q.K^T (4 key-subtiles x 2 k-halves) ----
        floatx4 s[4];
        #pragma unroll
        for (int ks = 0; ks < 4; ks++) {
            s[ks] = (floatx4){0.f, 0.f, 0.f, 0.f};
            const int krow = ks * 16 + cl;
            short8 kf0 = *(const short8*)&Ks[krow * 64 + fsA * 8];
            short8 kf1 = *(const short8*)&Ks[krow * 64 + fsB * 8];
            s[ks] = __builtin_amdgcn_mfma_f32_16x16x32_bf16(qa0, kf0, s[ks], 0, 0, 0);
            s[ks] = __builtin_amdgcn_mfma_f32_16x16x32_bf16(qa1, kf1, s[ks], 0, 0, 0);
        }

        // ---- scale + causal mask (last tile only) ----
        const bool last = (t == ntiles - 1);
        #pragma unroll
        for (int ks = 0; ks < 4; ks++)
            #pragma unroll
            for (int r = 0; r < 4; r++) {
                float sv = s[ks][r] * 0.125f;
                if (last && (j0 + ks * 16 + cl > qg_base + quad * 4 + r))
                    sv = -INFINITY;
                s[ks][r] = sv;
            }

        // ---- online softmax (register state, 16-lane shfl reductions) ----
        float alpha[4], rsum[4];
        #pragma unroll
        for (int r = 0; r < 4; r++) {
            float mx = fmaxf(fmaxf(s[0][r], s[1][r]), fmaxf(s[2][r], s[3][r]));
            mx = fmaxf(mx, __shfl_xor(mx, 1));
            mx = fmaxf(mx, __shfl_xor(mx, 2));
            mx = fmaxf(mx, __shfl_xor(mx, 4));
            mx = fmaxf(mx, __shfl_xor(mx, 8));
            const float mn = fmaxf(m_[r], mx);
            alpha[r] = __expf(m_[r] - mn);
            m_[r] = mn;
            rsum[r] = 0.f;
        }
        #pragma unroll
        for (int ks = 0; ks < 4; ks++) {
            #pragma unroll
            for (int r = 0; r < 4; r++) {
                float p = __expf(s[ks][r] - m_[r]);
                rsum[r] += p;
                const int q = quad * 4 + r;
                const int chunk = ks * 2 + (cl >> 3);
                const int slot = (chunk + q) & 7;
                Ps[w * 1024 + q * 64 + slot * 8 + (cl & 7)] = (short)f2bf(p);
            }
        }
        #pragma unroll
        for (int r = 0; r < 4; r++) {
            float t2 = rsum[r];
            t2 += __shfl_xor(t2, 1);
            t2 += __shfl_xor(t2, 2);
            t2 += __shfl_xor(t2, 4);
            t2 += __shfl_xor(t2, 8);
            l_[r] = l_[r] * alpha[r] + t2;
            o[0][r] *= alpha[r]; o[1][r] *= alpha[r];
            o[2][r] *= alpha[r]; o[3][r] *= alpha[r];
        }

        // wave-private LDS write->read: drain ds queue, pin ordering
        __builtin_amdgcn_s_waitcnt(0xc07f);   // lgkmcnt(0)
        __builtin_amdgcn_wave_barrier();

        // ---- O += P.V ----
        short8 pf0 = *(const short8*)&Ps[w * 1024 + cl * 64 + psA * 8];
        short8 pf1 = *(const short8*)&Ps[w * 1024 + cl * 64 + psB * 8];
        #pragma unroll
        for (int nt = 0; nt < 4; nt++) {
            const int drow = nt * 16 + cl;
            short8 vf0 = *(const short8*)&Vs[drow * 64 + fsA * 8];
            short8 vf1 = *(const short8*)&Vs[drow * 64 + fsB * 8];
            o[nt] = __builtin_amdgcn_mfma_f32_16x16x32_bf16(pf0, vf0, o[nt], 0, 0, 0);
            o[nt] = __builtin_amdgcn_mfma_f32_16x16x32_bf16(pf1, vf1, o[nt], 0, 0, 0);
        }
    }

    // ---- normalize + store Yatt bf16 [B][T][C] ----
    #pragma unroll
    for (int r = 0; r < 4; r++) {
        const float inv = 1.0f / l_[r];
        const int qrow = q0 + w * 16 + quad * 4 + r;
        short* yb = Yatt + ((size_t)b * TT + qrow) * CC + h * HD + cl;
        #pragma unroll
        for (int nt = 0; nt < 4; nt++)
            yb[nt * 16] = (short)f2bf(o[nt][r] * inv);
    }
}

// ---------------------------------------------------------------------------
// Kernel: proj MFMA GEMM. A = Yatt [2048][1024] bf16, B = WpT [1024][1024],
// C = out fp32 [2048][1024].
// ---------------------------------------------------------------------------
__global__ __launch_bounds__(256)
void proj_gemm(const short* __restrict__ A, const short* __restrict__ Bt,
               float* __restrict__ Co)
{
    __shared__ short As[128 * 32];
    __shared__ short Bs[128 * 32];
    const int row0 = blockIdx.y * 128, col0 = blockIdx.x * 128;
    const int tid = threadIdx.x;
    const int w = tid >> 6, l = tid & 63, quad = l >> 4, cl = l & 15;
    const int wr = w >> 1, wc = w & 1;

    const int sr = tid >> 1, sc = (tid & 1) << 1;
    const short* ga = A + (size_t)(row0 + sr) * CC + sc * 8;
    const short* gb = Bt + (size_t)(col0 + sr) * CC + sc * 8;
    const int rot = (sr & 15) >> 1;
    const int sl0 = (sc + rot) & 3, sl1 = (sc + 1 + rot) & 3;
    const int fs = (quad + (cl >> 1)) & 3;

    floatx4 acc[4][4];
    #pragma unroll
    for (int mi = 0; mi < 4; mi++)
        #pragma unroll
        for (int ni = 0; ni < 4; ni++) acc[mi][ni] = (floatx4){0.f, 0.f, 0.f, 0.f};

    for (int k0 = 0; k0 < CC; k0 += 32) {
        short8 a0 = *(const short8*)(ga + k0);
        short8 a1 = *(const short8*)(ga + k0 + 8);
        short8 b0 = *(const short8*)(gb + k0);
        short8 b1 = *(const short8*)(gb + k0 + 8);
        __syncthreads();
        *(short8*)&As[sr * 32 + sl0 * 8] = a0;
        *(short8*)&As[sr * 32 + sl1 * 8] = a1;
        *(short8*)&Bs[sr * 32 + sl0 * 8] = b0;
        *(short8*)&Bs[sr * 32 + sl1 * 8] = b1;
        __syncthreads();
        short8 af[4], bf[4];
        #pragma unroll
        for (int mi = 0; mi < 4; mi++)
            af[mi] = *(const short8*)&As[(wr * 64 + mi * 16 + cl) * 32 + fs * 8];
        #pragma unroll
        for (int ni = 0; ni < 4; ni++)
            bf[ni] = *(const short8*)&Bs[(wc * 64 + ni * 16 + cl) * 32 + fs * 8];
        #pragma unroll
        for (int mi = 0; mi < 4; mi++)
            #pragma unroll
            for (int ni = 0; ni < 4; ni++)
                acc[mi][ni] = __builtin_amdgcn_mfma_f32_16x16x32_bf16(
                    af[mi], bf[ni], acc[mi][ni], 0, 0, 0);
    }
    #pragma unroll
    for (int mi = 0; mi < 4; mi++)
        #pragma unroll
        for (int ni = 0; ni < 4; ni++)
            #pragma unroll
            for (int r = 0; r < 4; r++)
                Co[(size_t)(row0 + wr * 64 + mi * 16 + quad * 4 + r) * CC
                   + col0 + wc * 64 + ni * 16 + cl] = acc[mi][ni][r];
}

// ---------------------------------------------------------------------------
extern "C" void kernel_launch(void* const* d_in, const int* in_sizes, int n_in,
                              void* d_out, int out_size, void* d_ws, size_t ws_size,
                              hipStream_t stream)
{
    (void)in_sizes; (void)n_in; (void)out_size; (void)ws_size;
    const float* x      = (const float*)d_in[0];
    const float* stm    = (const float*)d_in[1];
    // d_in[2] = long_q: unused (output slice only covers query rows >= L+S)
    const float* long_k = (const float*)d_in[3];
    const float* long_v = (const float*)d_in[4];
    const float* w_attn = (const float*)d_in[5];
    const float* w_proj = (const float*)d_in[6];
    float* out = (float*)d_out;

    short* Xb   = (short*)d_ws;                 // 3,145,728
    short* WaT  = Xb   + (size_t)3145728;       // 3,145,728
    short* WpT  = WaT  + (size_t)3145728;       // 1,048,576
    short* Qb   = WpT  + (size_t)1048576;       // 2,097,152
    short* Kb   = Qb   + (size_t)2097152;       // 5,242,880
    short* Vtmp = Kb   + (size_t)5242880;       // 5,242,880
    short* Vtr  = Vtmp + (size_t)5242880;       // 5,242,880
    short* Yb   = Vtr  + (size_t)5242880;       // 2,097,152  (total ~54.7 MB)

    cast_xcat<<<3072, 256, 0, stream>>>(x, stm, Xb);
    wtrans<<<dim3(96, 32), 256, 0, stream>>>(w_attn, WaT, CC, C3);
    wtrans<<<dim3(32, 32), 256, 0, stream>>>(w_proj, WpT, CC, CC);
    copy_longkv<<<2048, 256, 0, stream>>>(long_k, long_v, Kb, Vtmp);

    qkv_gemm<<<dim3(24, 12, 2), 256, 0, stream>>>(Xb, WaT, Qb, Kb, Vtmp);
    vtrans<<<dim3(40, 32), 256, 0, stream>>>(Vtmp, Vtr);

    attn_mfma<<<dim3(32, 16), 256, 0, stream>>>(Qb, Kb, Vtr, Yb);

    proj_gemm<<<dim3(8, 16), 256, 0, stream>>>(Yb, WpT, out);
}